// Round 19
// baseline (155.971 us; speedup 1.0000x reference)
//
#include <hip/hip_runtime.h>
#include <hip/hip_bf16.h>

#define BB 4
#define NN 200
#define HH 300
#define GF 20             // g-frags of 16 (G padded to 320; frag 19 zero)
#define BM 128            // rows per block (16 per wave, 8 waves)

typedef __attribute__((ext_vector_type(8))) short short8;
typedef __attribute__((ext_vector_type(4))) float float4v;

static __device__ __forceinline__ ushort f2bf(float x) {
    union { float f; uint u; } v; v.f = x;
    uint r = v.u + 0x7FFFu + ((v.u >> 16) & 1u);  // RNE
    return (ushort)(r >> 16);
}

// 8 f32 -> 8 bf16 (RNE) via v_cvt_pk_bf16_f32
static __device__ __forceinline__ short8 pack8_cvt(float4v a, float4v b) {
    uint u0, u1, u2, u3;
    asm("v_cvt_pk_bf16_f32 %0, %1, %2" : "=v"(u0) : "v"(a[0]), "v"(a[1]));
    asm("v_cvt_pk_bf16_f32 %0, %1, %2" : "=v"(u1) : "v"(a[2]), "v"(a[3]));
    asm("v_cvt_pk_bf16_f32 %0, %1, %2" : "=v"(u2) : "v"(b[0]), "v"(b[1]));
    asm("v_cvt_pk_bf16_f32 %0, %1, %2" : "=v"(u3) : "v"(b[2]), "v"(b[3]));
    union { uint u[4]; short8 s; } r;
    r.u[0] = u0; r.u[1] = u1; r.u[2] = u2; r.u[3] = u3;
    return r.s;
}

static __device__ __forceinline__ void gload_lds16(const void* g, void* l) {
    __builtin_amdgcn_global_load_lds(
        (const __attribute__((address_space(1))) unsigned int*)g,
        (__attribute__((address_space(3))) unsigned int*)l, 16, 0, 0);
}

// Pack U_w (g,h) f32 -> bf16 in MFMA frag order (ks-major, full G):
// Bp[((ks*GF+gf)*64 + lane)*8 + j] = Uw[g=gf*16+(lane&15)][h=ks*32+(lane>>4)*8+j], 0 if OOB
__global__ void pack_u(const float* __restrict__ Uw, ushort* __restrict__ Bp) {
    int idx = blockIdx.x * 256 + threadIdx.x;
    if (idx >= 10 * GF * 64) return;
    int lane = idx & 63;
    int kg = idx >> 6;
    int gf = kg % GF, ks = kg / GF;
    int g = gf * 16 + (lane & 15);
    int h0 = ks * 32 + (lane >> 4) * 8;
    ushort v[8];
#pragma unroll
    for (int j = 0; j < 8; ++j) {
        int h = h0 + j;
        v[j] = (g < HH && h < HH) ? f2bf(Uw[g * HH + h]) : (ushort)0;
    }
    *reinterpret_cast<short8*>(Bp + (size_t)idx * 8) = *reinterpret_cast<const short8*>(v);
}

// Vx[b,n,g] = x@Vw^T + Vb + 0.5*Ub  (Ub folded). 4 rows/block (200 blocks):
// x rows staged in LDS (broadcast reads), Vw read once per block (72 MB total L2).
__global__ void vx_kernel(const float* __restrict__ x, const float* __restrict__ Vw,
                          const float* __restrict__ Vb, const float* __restrict__ Ub,
                          float* __restrict__ Vx) {
    __shared__ __align__(16) float xs[4][304];
    const int tid = threadIdx.x;
    const int row0 = blockIdx.x * 4;
    for (int i = tid; i < 300; i += 256) {           // FIX R18: 300 float4 loads, 256 threads
        int rr = i / 75, c = (i % 75) * 4;
        *reinterpret_cast<float4v*>(&xs[rr][c]) =
            *reinterpret_cast<const float4v*>(x + (size_t)(row0 + rr) * HH + c);
    }
    __syncthreads();
    for (int g = tid; g < HH; g += 256) {
        const float4v* wr = reinterpret_cast<const float4v*>(Vw + (size_t)g * HH);
        float a0 = 0.f, a1 = 0.f, a2 = 0.f, a3 = 0.f;
#pragma unroll 5
        for (int k = 0; k < 75; ++k) {
            float4v w = wr[k];
            float4v x0 = *reinterpret_cast<const float4v*>(&xs[0][k * 4]);
            float4v x1 = *reinterpret_cast<const float4v*>(&xs[1][k * 4]);
            float4v x2 = *reinterpret_cast<const float4v*>(&xs[2][k * 4]);
            float4v x3 = *reinterpret_cast<const float4v*>(&xs[3][k * 4]);
            a0 += w[0]*x0[0] + w[1]*x0[1] + w[2]*x0[2] + w[3]*x0[3];
            a1 += w[0]*x1[0] + w[1]*x1[1] + w[2]*x1[2] + w[3]*x1[3];
            a2 += w[0]*x2[0] + w[1]*x2[1] + w[2]*x2[2] + w[3]*x2[3];
            a3 += w[0]*x3[0] + w[1]*x3[1] + w[2]*x3[2] + w[3]*x3[3];
        }
        float bias = Vb[g] + 0.5f * Ub[g];
        Vx[(size_t)(row0 + 0) * HH + g] = bias + a0;
        Vx[(size_t)(row0 + 1) * HH + g] = bias + a1;
        Vx[(size_t)(row0 + 2) * HH + g] = bias + a2;
        Vx[(size_t)(row0 + 3) * HH + g] = bias + a3;
    }
}

// BM=128 x full G, 512 thr / 8 waves x 16 rows, BK=64 -> 5 phases. A wave-private
// (no LDS): per-lane f32 loads, 2 rotating reg sets, cvt in-reg. B double-buffered
// 2x40 KB via gload_lds, staged TWO chunks ahead; per phase each thread issues
// exactly 5 B-gloads + 4 A-loads = 9 -> WAITV(9) retires only the previous chunk.
// 80 KB LDS -> 2 blocks/CU = 16 waves/CU; half the B-stage L2 traffic of BM=64.
__launch_bounds__(512, 2)
__global__ void gemm_kernel(const float* __restrict__ e, const ushort* __restrict__ Bp,
                            const float* __restrict__ Vx, float* __restrict__ out) {
    __shared__ __align__(16) ushort Blds[2][20480];   // 2 x 40 KB (2 sub-ks x 20 frags)
    const int tid = threadIdx.x;
    const int w = tid >> 6, l = tid & 63;
    const int r = l & 15, q = l >> 4;
    const int m0 = blockIdx.x * BM;
    const float* rowp = e + (size_t)(m0 + w * 16 + r) * HH;   // lane-private A row

    float4v acc[GF];
#pragma unroll
    for (int f = 0; f < GF; ++f) acc[f] = (float4v){0.f, 0.f, 0.f, 0.f};

    // two rotating A reg sets, 4 float4 each (sub-ks 0: a0,a1 ; sub-ks 1: b0,b1)
    float4v s0a0, s0a1, s0b0, s0b1, s1a0, s1a1, s1b0, s1b1;

#define LOAD_A(KC_, S_) do {                                                    \
        int ca_ = (KC_) * 64 + q * 8;                                           \
        int cb_ = ca_ + 32;                                                     \
        const float* pa0_ = (ca_ + 4 <= HH) ? rowp + ca_ : e;                   \
        const float* pa1_ = (ca_ + 8 <= HH) ? rowp + ca_ + 4 : e;               \
        const float* pb0_ = (cb_ + 4 <= HH) ? rowp + cb_ : e;                   \
        const float* pb1_ = (cb_ + 8 <= HH) ? rowp + cb_ + 4 : e;               \
        S_##a0 = *reinterpret_cast<const float4v*>(pa0_);                       \
        S_##a1 = *reinterpret_cast<const float4v*>(pa1_);                       \
        S_##b0 = *reinterpret_cast<const float4v*>(pb0_);                       \
        S_##b1 = *reinterpret_cast<const float4v*>(pb1_);                       \
    } while (0)

    // B chunk (40 KB = ks 2KC_, 2KC_+1): 5 x 8 KB linear rounds -> 5 loads/thread
#define STAGE_B(KC_, P_) do {                                                   \
        const char* bs_ = (const char*)Bp + (size_t)(KC_) * 40960;              \
        char* bd_ = (char*)&Blds[P_][0];                                        \
        _Pragma("unroll")                                                       \
        for (int rd_ = 0; rd_ < 5; ++rd_)                                       \
            gload_lds16(bs_ + rd_ * 8192 + tid * 16, bd_ + rd_ * 8192 + tid * 16); \
    } while (0)

    // compute chunk KC_ from Blds[P_]: 2 sub-ks x 20 frags = 40 MFMA
#define COMPUTE(KC_, P_, S_) do {                                               \
        short8 fa0_ = pack8_cvt(S_##a0, S_##a1);                                \
        short8 fa1_ = pack8_cvt(S_##b0, S_##b1);                                \
        if ((KC_) == 4) {   /* ks=9: zero cols >= 300 (cols 288+q*8+j) */       \
            int c0_ = 288 + q * 8;                                              \
            _Pragma("unroll")                                                   \
            for (int j_ = 0; j_ < 8; ++j_)                                      \
                if (c0_ + j_ >= HH) fa1_[j_] = 0;                               \
        }                                                                       \
        const ushort* bb_ = &Blds[P_][l * 8];                                   \
        _Pragma("unroll")                                                       \
        for (int f_ = 0; f_ < GF; ++f_) {                                       \
            short8 bf_ = *reinterpret_cast<const short8*>(bb_ + f_ * 512);      \
            acc[f_] = __builtin_amdgcn_mfma_f32_16x16x32_bf16(bf_, fa0_, acc[f_], 0, 0, 0); \
        }                                                                       \
        _Pragma("unroll")                                                       \
        for (int f_ = 0; f_ < GF; ++f_) {                                       \
            short8 bf_ = *reinterpret_cast<const short8*>(bb_ + 10240 + f_ * 512); \
            acc[f_] = __builtin_amdgcn_mfma_f32_16x16x32_bf16(bf_, fa1_, acc[f_], 0, 0, 0); \
        }                                                                       \
    } while (0)

#define WAITV(N_) do {                                                          \
        __builtin_amdgcn_sched_barrier(0);                                      \
        asm volatile("s_waitcnt vmcnt(" #N_ ")" ::: "memory");                  \
        __builtin_amdgcn_sched_barrier(0);                                      \
    } while (0)

#define BARX() do {                                                             \
        asm volatile("s_waitcnt lgkmcnt(0)" ::: "memory");                      \
        __builtin_amdgcn_s_barrier();                                           \
        __builtin_amdgcn_sched_barrier(0);                                      \
    } while (0)

    // ---- prologue: chunks 0,1 in flight; retire chunk 0 (9 loads) ----
    STAGE_B(0, 0); LOAD_A(0, s0);
    STAGE_B(1, 1); LOAD_A(1, s1);
    WAITV(9); BARX();

    // ---- 5 phases, stage-2-ahead ----
    COMPUTE(0, 0, s0); BARX();
    STAGE_B(2, 0); LOAD_A(2, s0); WAITV(9); BARX();
    COMPUTE(1, 1, s1); BARX();
    STAGE_B(3, 1); LOAD_A(3, s1); WAITV(9); BARX();
    COMPUTE(2, 0, s0); BARX();
    STAGE_B(4, 0); LOAD_A(4, s0); WAITV(9); BARX();
    COMPUTE(3, 1, s1); BARX();
    WAITV(0); BARX();
    COMPUTE(4, 0, s0);

    // ---- epilogue: out[m][g] = acc + Vx'[i][g] + Vx'[j][g]  (Ub folded in Vx') ----
    {
        const int m = m0 + w * 16 + r;
        int j = m % NN;
        int ti = m / NN;        // b*NN + i
        int b = ti / NN;
        const float* vi = Vx + (size_t)ti * HH;
        const float* vj = Vx + (size_t)(b * NN + j) * HH;
        float* orow = out + (size_t)m * HH;
#pragma unroll
        for (int f = 0; f < GF - 1; ++f) {
            int g0 = f * 16 + q * 4;
            if (g0 + 4 <= HH) {
                float4v vi4 = *reinterpret_cast<const float4v*>(vi + g0);
                float4v vj4 = *reinterpret_cast<const float4v*>(vj + g0);
                *reinterpret_cast<float4v*>(orow + g0) = acc[f] + vi4 + vj4;
            }
        }
    }
#undef LOAD_A
#undef STAGE_B
#undef COMPUTE
#undef WAITV
#undef BARX
}

extern "C" void kernel_launch(void* const* d_in, const int* in_sizes, int n_in,
                              void* d_out, int out_size, void* d_ws, size_t ws_size,
                              hipStream_t stream) {
    const float* x  = (const float*)d_in[0];
    const float* e  = (const float*)d_in[1];
    const float* Uw = (const float*)d_in[2];
    const float* Ub = (const float*)d_in[3];
    const float* Vw = (const float*)d_in[4];
    const float* Vb = (const float*)d_in[5];
    float* out = (float*)d_out;

    ushort* Bp = (ushort*)d_ws;                              // 204,800 B (frag-packed bf16 U_w)
    float*  Vx = (float*)((char*)d_ws + 204800);             // 960,000 B

    pack_u<<<50, 256, 0, stream>>>(Uw, Bp);
    vx_kernel<<<200, 256, 0, stream>>>(x, Vw, Vb, Ub, Vx);
    gemm_kernel<<<160000 / BM, 512, 0, stream>>>(e, Bp, Vx, out);
}